// Round 4
// baseline (160.013 us; speedup 1.0000x reference)
//
#include <hip/hip_runtime.h>
#include <hip/hip_bf16.h>
#include <stdint.h>

// Problem constants (B=8, S=2048, E=1024, H=128, DK=8)
#define M_DIM 16384   // B*S
#define N_DIM 1024    // E (output features)
#define K_DIM 1024    // E (reduction)

typedef __attribute__((ext_vector_type(8))) short short8;
typedef __attribute__((ext_vector_type(4))) float f32x4;

// async global->LDS, 16B per lane. LDS dest must be wave-uniform base + lane*16.
#define GLD_LDS(g, l) __builtin_amdgcn_global_load_lds( \
    (const __attribute__((address_space(1))) unsigned int*)(g), \
    (__attribute__((address_space(3))) unsigned int*)(l), 16, 0, 0)

__device__ __forceinline__ unsigned short f2bf(float f) {
  union { float f; unsigned int u; } v;
  v.f = f;
  unsigned int u = v.u + 0x7FFFu + ((v.u >> 16) & 1u);  // RNE
  return (unsigned short)(u >> 16);
}

// Fused prep: blocks [0, 8192) -> A_bf16[m,k] = bf16(cos(x[m,k]+theta[k]));
//             blocks [8192, 8704) -> W_bf16 cast. 8 elems/thread, all 16B I/O.
#define PREP_A_BLOCKS (M_DIM * K_DIM / (256 * 8))   // 8192
#define PREP_W_BLOCKS (N_DIM * K_DIM / (256 * 8))   // 512
__global__ __launch_bounds__(256) void prep_all(const float* __restrict__ x,
                                                const float* __restrict__ theta,
                                                const float* __restrict__ W,
                                                unsigned short* __restrict__ A,
                                                unsigned short* __restrict__ Wb) {
  if (blockIdx.x < PREP_A_BLOCKS) {
    const long i = ((long)blockIdx.x * 256 + threadIdx.x) * 8;
    const int k = (int)(i & (K_DIM - 1));
    float4 x0 = *(const float4*)(x + i);
    float4 x1 = *(const float4*)(x + i + 4);
    float4 t0 = *(const float4*)(theta + k);
    float4 t1 = *(const float4*)(theta + k + 4);
    union { unsigned short s[8]; short8 v; } o;
    o.s[0] = f2bf(__cosf(x0.x + t0.x));
    o.s[1] = f2bf(__cosf(x0.y + t0.y));
    o.s[2] = f2bf(__cosf(x0.z + t0.z));
    o.s[3] = f2bf(__cosf(x0.w + t0.w));
    o.s[4] = f2bf(__cosf(x1.x + t1.x));
    o.s[5] = f2bf(__cosf(x1.y + t1.y));
    o.s[6] = f2bf(__cosf(x1.z + t1.z));
    o.s[7] = f2bf(__cosf(x1.w + t1.w));
    *(short8*)(A + i) = o.v;
  } else {
    const long i = ((long)(blockIdx.x - PREP_A_BLOCKS) * 256 + threadIdx.x) * 8;
    float4 w0 = *(const float4*)(W + i);
    float4 w1 = *(const float4*)(W + i + 4);
    union { unsigned short s[8]; short8 v; } o;
    o.s[0] = f2bf(w0.x); o.s[1] = f2bf(w0.y); o.s[2] = f2bf(w0.z); o.s[3] = f2bf(w0.w);
    o.s[4] = f2bf(w1.x); o.s[5] = f2bf(w1.y); o.s[6] = f2bf(w1.z); o.s[7] = f2bf(w1.w);
    *(short8*)(Wb + i) = o.v;
  }
}

// C[m,n] = sum_k A[m,k]*Bt[n,k] + bias[n].  A:[M,K] bf16, Bt:[N,K] bf16, C:[M,N] f32.
//
// R5: 8-phase counted-vmcnt pipeline, RACE-FIXED issue rotation.
// r3 bug: STAGE_A(u0,t+2,·) was issued in the SAME phase that ds_reads unit u0
// (A units are read in two phases: LO rows 0-63, HI rows 64-127) -> another
// wave's staging write could land before a slower wave's ds_read. Fixed
// rotation (no phase stages a unit it reads; every target last read >=1
// barrier earlier):
//   phase 4t+0 (LO kh0): issue A-kh1(t+1)   [target last read 4t-1]
//   phase 4t+1 (HI kh0): issue B-kh1(t+1)   [last read 4t-2]; vmcnt(8)
//   phase 4t+2 (LO kh1): issue A-kh0(t+2)   [last read 4t+1]
//   phase 4t+3 (HI kh1): issue B-kh0(t+2)   [last read 4t];   vmcnt(8)
// Wait ledger (2 ops/stage, per wave): vmcnt(8) at end of each HI phase leaves
// exactly the last 4 stages in flight and forces the two units the next LO
// phase reads. Prologue: 6 units (A0k0,B0k0,A0k1,B0k1,A1k0,B1k0) + vmcnt(8).
// Tail: t14 [-,8,-,4], t15 [-,0,-,-]. Never drains below 2 units until t15.
//
// LDS unit = 16 KB = 256 rows x 32 k (one operand, one tile, one K-half).
// chunk(row,kc) at slot (row>>7)*512 + ((row>>3)&15)*32 + kc*8 + (row&7);
// linear in global_load_lds dest d=i*512+tid (bijection re-verified), and
// ds_read_b128 of 8 consecutive frag rows at fixed kc covers 8 distinct 16B
// slots spanning all 32 banks -> conflict-free (2-way lane aliasing only).
// Read base: elem(row,kc=fq) = (row>>3)*256 + fq*64 + (row&7)*8.
//
// Grid: 256 blocks = 1/CU (128 KB LDS). XCD-banded map unchanged.
__global__ __launch_bounds__(512, 2) void gemm_bt(const unsigned short* __restrict__ A,
                                                  const unsigned short* __restrict__ Bt,
                                                  const float* __restrict__ bias,
                                                  float* __restrict__ C) {
  constexpr int NTT = K_DIM / 64;  // 16 K-tiles
  __shared__ unsigned short As[4 * 8192];  // 64 KB: units [dbuf][kh]
  __shared__ unsigned short Bs[4 * 8192];  // 64 KB
  const int tid = threadIdx.x;

  const int L = blockIdx.y * 4 + blockIdx.x;  // linear dispatch id, 0..255
  const int xcd = L & 7;
  const int idx = L >> 3;
  const int by = xcd * 8 + (idx >> 2);  // M-tile 0..63, banded per XCD
  const int bx = idx & 3;               // N-tile 0..3
  const int m0 = by * 256;
  const int n0 = bx * 256;

  const int lane = tid & 63;
  const int wave = tid >> 6;        // 0..7
  const int wm = (wave >> 2) * 128; // wave origin in M (0,128)
  const int wn = (wave & 3) * 64;   // wave origin in N (0,64,128,192)
  const int fr = lane & 15;
  const int fq = lane >> 4;

  f32x4 acc[8][4] = {};

  // Staging source: thread tid, issue i in {0,1}: row = i*128 + srow, chunk kc.
  const int srow = ((tid >> 5) << 3) | (tid & 7);  // 0..127
  const int kc = (tid >> 3) & 3;
  const unsigned short* AgU = A + (long)(m0 + srow) * K_DIM + kc * 8;
  const unsigned short* BgU = Bt + (long)(n0 + srow) * K_DIM + kc * 8;
  unsigned short* AsD = As + tid * 8;
  unsigned short* BsD = Bs + tid * 8;

#define STAGE_A(UNIT, TAU, KH) do { \
    const unsigned short* g_ = AgU + (TAU) * 64 + (KH) * 32; \
    unsigned short* d_ = AsD + (UNIT) * 8192; \
    GLD_LDS(g_, d_); \
    GLD_LDS(g_ + (long)128 * K_DIM, d_ + 4096); \
  } while (0)
#define STAGE_B(UNIT, TAU, KH) do { \
    const unsigned short* g_ = BgU + (TAU) * 64 + (KH) * 32; \
    unsigned short* d_ = BsD + (UNIT) * 8192; \
    GLD_LDS(g_, d_); \
    GLD_LDS(g_ + (long)128 * K_DIM, d_ + 4096); \
  } while (0)

  // Fragment read bases: elem(row,kc=fq) = (row>>3)*256 + fq*64 + (row&7)*8.
  const int baseA = ((wm >> 3) + (fr >> 3)) * 256 + fq * 64 + (fr & 7) * 8;
  const int baseB = ((wn >> 3) + (fr >> 3)) * 256 + fq * 64 + (fr & 7) * 8;

  short8 bf0, bf1, bf2, bf3;

#define MFMA16(IH, A0, A1, A2, A3) do { \
    __builtin_amdgcn_s_setprio(1); \
    acc[(IH)*4+0][0] = __builtin_amdgcn_mfma_f32_16x16x32_bf16(A0, bf0, acc[(IH)*4+0][0], 0, 0, 0); \
    acc[(IH)*4+0][1] = __builtin_amdgcn_mfma_f32_16x16x32_bf16(A0, bf1, acc[(IH)*4+0][1], 0, 0, 0); \
    acc[(IH)*4+0][2] = __builtin_amdgcn_mfma_f32_16x16x32_bf16(A0, bf2, acc[(IH)*4+0][2], 0, 0, 0); \
    acc[(IH)*4+0][3] = __builtin_amdgcn_mfma_f32_16x16x32_bf16(A0, bf3, acc[(IH)*4+0][3], 0, 0, 0); \
    acc[(IH)*4+1][0] = __builtin_amdgcn_mfma_f32_16x16x32_bf16(A1, bf0, acc[(IH)*4+1][0], 0, 0, 0); \
    acc[(IH)*4+1][1] = __builtin_amdgcn_mfma_f32_16x16x32_bf16(A1, bf1, acc[(IH)*4+1][1], 0, 0, 0); \
    acc[(IH)*4+1][2] = __builtin_amdgcn_mfma_f32_16x16x32_bf16(A1, bf2, acc[(IH)*4+1][2], 0, 0, 0); \
    acc[(IH)*4+1][3] = __builtin_amdgcn_mfma_f32_16x16x32_bf16(A1, bf3, acc[(IH)*4+1][3], 0, 0, 0); \
    acc[(IH)*4+2][0] = __builtin_amdgcn_mfma_f32_16x16x32_bf16(A2, bf0, acc[(IH)*4+2][0], 0, 0, 0); \
    acc[(IH)*4+2][1] = __builtin_amdgcn_mfma_f32_16x16x32_bf16(A2, bf1, acc[(IH)*4+2][1], 0, 0, 0); \
    acc[(IH)*4+2][2] = __builtin_amdgcn_mfma_f32_16x16x32_bf16(A2, bf2, acc[(IH)*4+2][2], 0, 0, 0); \
    acc[(IH)*4+2][3] = __builtin_amdgcn_mfma_f32_16x16x32_bf16(A2, bf3, acc[(IH)*4+2][3], 0, 0, 0); \
    acc[(IH)*4+3][0] = __builtin_amdgcn_mfma_f32_16x16x32_bf16(A3, bf0, acc[(IH)*4+3][0], 0, 0, 0); \
    acc[(IH)*4+3][1] = __builtin_amdgcn_mfma_f32_16x16x32_bf16(A3, bf1, acc[(IH)*4+3][1], 0, 0, 0); \
    acc[(IH)*4+3][2] = __builtin_amdgcn_mfma_f32_16x16x32_bf16(A3, bf2, acc[(IH)*4+3][2], 0, 0, 0); \
    acc[(IH)*4+3][3] = __builtin_amdgcn_mfma_f32_16x16x32_bf16(A3, bf3, acc[(IH)*4+3][3], 0, 0, 0); \
    __builtin_amdgcn_s_setprio(0); \
  } while (0)

#define BAR() do { asm volatile("" ::: "memory"); __builtin_amdgcn_s_barrier(); \
                   asm volatile("" ::: "memory"); } while (0)
#define VMW(N) asm volatile("s_waitcnt vmcnt(" #N ")" ::: "memory")

#define PHASE_LO(Au, Bu, ISSUE, WAIT) do { \
    BAR(); \
    ISSUE; \
    bf0 = *(const short8*)((Bu) + baseB + 0); \
    bf1 = *(const short8*)((Bu) + baseB + 512); \
    bf2 = *(const short8*)((Bu) + baseB + 1024); \
    bf3 = *(const short8*)((Bu) + baseB + 1536); \
    { short8 a0 = *(const short8*)((Au) + baseA + 0); \
      short8 a1 = *(const short8*)((Au) + baseA + 512); \
      short8 a2 = *(const short8*)((Au) + baseA + 1024); \
      short8 a3 = *(const short8*)((Au) + baseA + 1536); \
      MFMA16(0, a0, a1, a2, a3); } \
    WAIT; \
  } while (0)

#define PHASE_HI(Au, ISSUE, WAIT) do { \
    BAR(); \
    ISSUE; \
    { short8 a0 = *(const short8*)((Au) + baseA + 2048); \
      short8 a1 = *(const short8*)((Au) + baseA + 2560); \
      short8 a2 = *(const short8*)((Au) + baseA + 3072); \
      short8 a3 = *(const short8*)((Au) + baseA + 3584); \
      MFMA16(1, a0, a1, a2, a3); } \
    WAIT; \
  } while (0)

  // Prologue: tile0 {Ak0,Bk0,Ak1,Bk1} + tile1 {Ak0,Bk0}; wait for tile0-kh0.
  STAGE_A(0, 0, 0);
  STAGE_B(0, 0, 0);
  STAGE_A(1, 0, 1);
  STAGE_B(1, 0, 1);
  STAGE_A(2, 1, 0);
  STAGE_B(2, 1, 0);
  VMW(8);  // A-kh0(0), B-kh0(0) landed; 4 stages in flight

  for (int t = 0; t < NTT - 2; ++t) {   // t = 0..13
    const int db = t & 1;
    const int u0 = db * 2;              // this tile kh0 unit
    const int u1 = db * 2 + 1;          // this tile kh1 unit
    const int v1 = (db ^ 1) * 2 + 1;    // next tile kh1 unit
    const unsigned short* Au0 = As + u0 * 8192;
    const unsigned short* Bu0 = Bs + u0 * 8192;
    const unsigned short* Au1 = As + u1 * 8192;
    const unsigned short* Bu1 = Bs + u1 * 8192;
    PHASE_LO(Au0, Bu0, STAGE_A(v1, t + 1, 1), (void)0);
    PHASE_HI(Au0,      STAGE_B(v1, t + 1, 1), VMW(8));
    PHASE_LO(Au1, Bu1, STAGE_A(u0, t + 2, 0), (void)0);
    PHASE_HI(Au1,      STAGE_B(u0, t + 2, 0), VMW(8));
  }
  { // t = 14 (db=0): stage only kh1(15); wind down 8 -> 4
    const unsigned short* Au0 = As;
    const unsigned short* Bu0 = Bs;
    const unsigned short* Au1 = As + 8192;
    const unsigned short* Bu1 = Bs + 8192;
    PHASE_LO(Au0, Bu0, STAGE_A(3, 15, 1), (void)0);
    PHASE_HI(Au0,      STAGE_B(3, 15, 1), VMW(8));
    PHASE_LO(Au1, Bu1, (void)0,           (void)0);
    PHASE_HI(Au1,      (void)0,           VMW(4));
  }
  { // t = 15 (db=1): drain 4 -> 0
    const unsigned short* Au0 = As + 2 * 8192;
    const unsigned short* Bu0 = Bs + 2 * 8192;
    const unsigned short* Au1 = As + 3 * 8192;
    const unsigned short* Bu1 = Bs + 3 * 8192;
    PHASE_LO(Au0, Bu0, (void)0, (void)0);
    PHASE_HI(Au0,      (void)0, VMW(0));
    PHASE_LO(Au1, Bu1, (void)0, (void)0);
    PHASE_HI(Au1,      (void)0, (void)0);
  }

  // Epilogue: D[row=(lane>>4)*4+r][col=lane&15] per 16x16 frag (m89-verified).
  const int cn = lane & 15;
  const int rq = (lane >> 4) * 4;
#pragma unroll
  for (int j = 0; j < 4; ++j) {
    const int n = n0 + wn + j * 16 + cn;
    const float bv = bias[n];
#pragma unroll
    for (int i = 0; i < 8; ++i) {
      const long mb = (long)(m0 + wm + i * 16 + rq) * N_DIM + n;
#pragma unroll
      for (int r = 0; r < 4; ++r)
        C[mb + (long)r * N_DIM] = acc[i][j][r] + bv;
    }
  }
}

extern "C" void kernel_launch(void* const* d_in, const int* in_sizes, int n_in,
                              void* d_out, int out_size, void* d_ws, size_t ws_size,
                              hipStream_t stream) {
  const float* x = (const float*)d_in[0];      // [8,2048,1024]
  const float* theta = (const float*)d_in[1];  // [128,8] -> flat 1024
  const float* W = (const float*)d_in[2];      // [1024,1024]
  const float* b = (const float*)d_in[3];      // [1024]
  float* out = (float*)d_out;                  // [8,2048,1024] f32

  unsigned short* Abf = (unsigned short*)d_ws;                   // 33.5 MB
  unsigned short* Wbf = Abf + (size_t)M_DIM * K_DIM;             // +2 MB

  hipLaunchKernelGGL(prep_all, dim3(PREP_A_BLOCKS + PREP_W_BLOCKS), dim3(256), 0,
                     stream, x, theta, W, Abf, Wbf);
  hipLaunchKernelGGL(gemm_bt, dim3(N_DIM / 256, M_DIM / 256), dim3(512), 0, stream,
                     Abf, Wbf, b, out);
}

// Round 5
// 155.737 us; speedup vs baseline: 1.0275x; 1.0275x over previous
//
#include <hip/hip_runtime.h>
#include <hip/hip_bf16.h>
#include <stdint.h>

// Problem constants (B=8, S=2048, E=1024, H=128, DK=8)
#define M_DIM 16384   // B*S
#define N_DIM 1024    // E (output features)
#define K_DIM 1024    // E (reduction)

typedef __attribute__((ext_vector_type(8))) short short8;
typedef __attribute__((ext_vector_type(4))) float f32x4;

// async global->LDS, 16B per lane. LDS dest must be wave-uniform base + lane*16.
#define GLD_LDS(g, l) __builtin_amdgcn_global_load_lds( \
    (const __attribute__((address_space(1))) unsigned int*)(g), \
    (__attribute__((address_space(3))) unsigned int*)(l), 16, 0, 0)

__device__ __forceinline__ unsigned short f2bf(float f) {
  union { float f; unsigned int u; } v;
  v.f = f;
  unsigned int u = v.u + 0x7FFFu + ((v.u >> 16) & 1u);  // RNE
  return (unsigned short)(u >> 16);
}

// Fused prep: blocks [0, 8192) -> A_bf16[m,k] = bf16(cos(x[m,k]+theta[k]));
//             blocks [8192, 8704) -> W_bf16 cast. 8 elems/thread, all 16B I/O.
#define PREP_A_BLOCKS (M_DIM * K_DIM / (256 * 8))   // 8192
#define PREP_W_BLOCKS (N_DIM * K_DIM / (256 * 8))   // 512
__global__ __launch_bounds__(256) void prep_all(const float* __restrict__ x,
                                                const float* __restrict__ theta,
                                                const float* __restrict__ W,
                                                unsigned short* __restrict__ A,
                                                unsigned short* __restrict__ Wb) {
  if (blockIdx.x < PREP_A_BLOCKS) {
    const long i = ((long)blockIdx.x * 256 + threadIdx.x) * 8;
    const int k = (int)(i & (K_DIM - 1));
    float4 x0 = *(const float4*)(x + i);
    float4 x1 = *(const float4*)(x + i + 4);
    float4 t0 = *(const float4*)(theta + k);
    float4 t1 = *(const float4*)(theta + k + 4);
    union { unsigned short s[8]; short8 v; } o;
    o.s[0] = f2bf(__cosf(x0.x + t0.x));
    o.s[1] = f2bf(__cosf(x0.y + t0.y));
    o.s[2] = f2bf(__cosf(x0.z + t0.z));
    o.s[3] = f2bf(__cosf(x0.w + t0.w));
    o.s[4] = f2bf(__cosf(x1.x + t1.x));
    o.s[5] = f2bf(__cosf(x1.y + t1.y));
    o.s[6] = f2bf(__cosf(x1.z + t1.z));
    o.s[7] = f2bf(__cosf(x1.w + t1.w));
    *(short8*)(A + i) = o.v;
  } else {
    const long i = ((long)(blockIdx.x - PREP_A_BLOCKS) * 256 + threadIdx.x) * 8;
    float4 w0 = *(const float4*)(W + i);
    float4 w1 = *(const float4*)(W + i + 4);
    union { unsigned short s[8]; short8 v; } o;
    o.s[0] = f2bf(w0.x); o.s[1] = f2bf(w0.y); o.s[2] = f2bf(w0.z); o.s[3] = f2bf(w0.w);
    o.s[4] = f2bf(w1.x); o.s[5] = f2bf(w1.y); o.s[6] = f2bf(w1.z); o.s[7] = f2bf(w1.w);
    *(short8*)(Wb + i) = o.v;
  }
}

// C[m,n] = sum_k A[m,k]*Bt[n,k] + bias[n].  A:[M,K] bf16, Bt:[N,K] bf16, C:[M,N] f32.
//
// R6: m201-faithful phase ordering. r5 regression diagnosed: barrier -> ds_read
// -> MFMA serialized LDS read-burst + latency into the MFMA path every phase
// (m196's "coarse split" −7-27% case). Now each phase is:
//   { ds_read (this phase's frags) ; issue 1 stage ; [counted vmcnt] ;
//     s_barrier ; lgkmcnt(0) ; sched_barrier(0) ; setprio(1) 16 MFMA setprio(0) }
// Read latency overlaps the barrier rendezvous; fast wave's reads(p+1) overlap
// slow wave's MFMA(p).
//
// Anti-race (reads are pre-barrier now, so a slow wave past barrier(p-1) may
// still have readset(p-1) reads pending when a fast wave issues stage(p)):
// stage-target(p) must avoid readset(p-1) U readset(p). Readsets per tile t:
// P1{A0,B0} P2{A0} P3{A1,B1} P4{A1}. Issue rotation (each target last read
// >=2 phases back, unit slots double-buffered by tile parity):
//   P1(t): B1(t+1) [slot last read P3(t-1)]   P2(t): A1(t+1) [P4(t-1)]
//   P3(t): B0(t+2) [P1(t)]                    P4(t): A0(t+2) [P2(t)]
// Waits (pre-barrier; vmcnt decrements in issue order): VMW(8) at P2 and P4 =
// force all but newest 4 stages. At P4(t) that forces A0/B0(t+1) (read P1/P2
// (t+1)); at P2(t) forces A1/B1(t) (read P3/P4(t)). Leads 4-6 phases.
// Prologue: B0A0(0),B1A1(0),B0A0(1) + VMW(8) (forces B0,A0(0)) + barrier.
// Tail: t14 [P2:VMW(8), P4:VMW(4)], t15 [P2:VMW(0)]. No drain before t15.
//
// LDS unit = 16 KB (one operand, one tile, one K-half), layout linear in
// global_load_lds dest and conflict-free for ds_read_b128 (r5-verified: 0
// bank conflicts). Grid 256 blocks = 1/CU; XCD-banded map unchanged.
__global__ __launch_bounds__(512, 2) void gemm_bt(const unsigned short* __restrict__ A,
                                                  const unsigned short* __restrict__ Bt,
                                                  const float* __restrict__ bias,
                                                  float* __restrict__ C) {
  constexpr int NTT = K_DIM / 64;  // 16 K-tiles
  __shared__ unsigned short As[4 * 8192];  // 64 KB: units [tile parity][kh]
  __shared__ unsigned short Bs[4 * 8192];  // 64 KB
  const int tid = threadIdx.x;

  const int L = blockIdx.y * 4 + blockIdx.x;  // linear dispatch id, 0..255
  const int xcd = L & 7;
  const int idx = L >> 3;
  const int by = xcd * 8 + (idx >> 2);  // M-tile 0..63, banded per XCD
  const int bx = idx & 3;               // N-tile 0..3
  const int m0 = by * 256;
  const int n0 = bx * 256;

  const int lane = tid & 63;
  const int wave = tid >> 6;        // 0..7
  const int wm = (wave >> 2) * 128; // wave origin in M (0,128)
  const int wn = (wave & 3) * 64;   // wave origin in N (0,64,128,192)
  const int fr = lane & 15;
  const int fq = lane >> 4;

  f32x4 acc[8][4] = {};

  // Staging source: thread tid, issue i in {0,1}: row = i*128 + srow, chunk kc.
  const int srow = ((tid >> 5) << 3) | (tid & 7);  // 0..127
  const int kc = (tid >> 3) & 3;
  const unsigned short* AgU = A + (long)(m0 + srow) * K_DIM + kc * 8;
  const unsigned short* BgU = Bt + (long)(n0 + srow) * K_DIM + kc * 8;
  unsigned short* AsD = As + tid * 8;
  unsigned short* BsD = Bs + tid * 8;

#define STAGE_A(UNIT, TAU, KH) do { \
    const unsigned short* g_ = AgU + (TAU) * 64 + (KH) * 32; \
    unsigned short* d_ = AsD + (UNIT) * 8192; \
    GLD_LDS(g_, d_); \
    GLD_LDS(g_ + (long)128 * K_DIM, d_ + 4096); \
  } while (0)
#define STAGE_B(UNIT, TAU, KH) do { \
    const unsigned short* g_ = BgU + (TAU) * 64 + (KH) * 32; \
    unsigned short* d_ = BsD + (UNIT) * 8192; \
    GLD_LDS(g_, d_); \
    GLD_LDS(g_ + (long)128 * K_DIM, d_ + 4096); \
  } while (0)

  // Fragment read bases: elem(row,kc=fq) = (row>>3)*256 + fq*64 + (row&7)*8.
  const int baseA = ((wm >> 3) + (fr >> 3)) * 256 + fq * 64 + (fr & 7) * 8;
  const int baseB = ((wn >> 3) + (fr >> 3)) * 256 + fq * 64 + (fr & 7) * 8;

  short8 bf0, bf1, bf2, bf3;

#define MFMA16(IH, A0, A1, A2, A3) do { \
    __builtin_amdgcn_s_setprio(1); \
    acc[(IH)*4+0][0] = __builtin_amdgcn_mfma_f32_16x16x32_bf16(A0, bf0, acc[(IH)*4+0][0], 0, 0, 0); \
    acc[(IH)*4+0][1] = __builtin_amdgcn_mfma_f32_16x16x32_bf16(A0, bf1, acc[(IH)*4+0][1], 0, 0, 0); \
    acc[(IH)*4+0][2] = __builtin_amdgcn_mfma_f32_16x16x32_bf16(A0, bf2, acc[(IH)*4+0][2], 0, 0, 0); \
    acc[(IH)*4+0][3] = __builtin_amdgcn_mfma_f32_16x16x32_bf16(A0, bf3, acc[(IH)*4+0][3], 0, 0, 0); \
    acc[(IH)*4+1][0] = __builtin_amdgcn_mfma_f32_16x16x32_bf16(A1, bf0, acc[(IH)*4+1][0], 0, 0, 0); \
    acc[(IH)*4+1][1] = __builtin_amdgcn_mfma_f32_16x16x32_bf16(A1, bf1, acc[(IH)*4+1][1], 0, 0, 0); \
    acc[(IH)*4+1][2] = __builtin_amdgcn_mfma_f32_16x16x32_bf16(A1, bf2, acc[(IH)*4+1][2], 0, 0, 0); \
    acc[(IH)*4+1][3] = __builtin_amdgcn_mfma_f32_16x16x32_bf16(A1, bf3, acc[(IH)*4+1][3], 0, 0, 0); \
    acc[(IH)*4+2][0] = __builtin_amdgcn_mfma_f32_16x16x32_bf16(A2, bf0, acc[(IH)*4+2][0], 0, 0, 0); \
    acc[(IH)*4+2][1] = __builtin_amdgcn_mfma_f32_16x16x32_bf16(A2, bf1, acc[(IH)*4+2][1], 0, 0, 0); \
    acc[(IH)*4+2][2] = __builtin_amdgcn_mfma_f32_16x16x32_bf16(A2, bf2, acc[(IH)*4+2][2], 0, 0, 0); \
    acc[(IH)*4+2][3] = __builtin_amdgcn_mfma_f32_16x16x32_bf16(A2, bf3, acc[(IH)*4+2][3], 0, 0, 0); \
    acc[(IH)*4+3][0] = __builtin_amdgcn_mfma_f32_16x16x32_bf16(A3, bf0, acc[(IH)*4+3][0], 0, 0, 0); \
    acc[(IH)*4+3][1] = __builtin_amdgcn_mfma_f32_16x16x32_bf16(A3, bf1, acc[(IH)*4+3][1], 0, 0, 0); \
    acc[(IH)*4+3][2] = __builtin_amdgcn_mfma_f32_16x16x32_bf16(A3, bf2, acc[(IH)*4+3][2], 0, 0, 0); \
    acc[(IH)*4+3][3] = __builtin_amdgcn_mfma_f32_16x16x32_bf16(A3, bf3, acc[(IH)*4+3][3], 0, 0, 0); \
    __builtin_amdgcn_s_setprio(0); \
  } while (0)

#define BAR() do { asm volatile("" ::: "memory"); __builtin_amdgcn_s_barrier(); \
                   asm volatile("" ::: "memory"); } while (0)
#define VMW(N) asm volatile("s_waitcnt vmcnt(" #N ")" ::: "memory")
#define LGKM0() do { asm volatile("s_waitcnt lgkmcnt(0)" ::: "memory"); \
                     __builtin_amdgcn_sched_barrier(0); } while (0)

  // Phase: reads -> stage-issue -> [vmcnt] -> barrier -> lgkmcnt(0) -> MFMA.
#define PHASE_LO(Au, Bu, ISSUE, WAITPRE) do { \
    bf0 = *(const short8*)((Bu) + baseB + 0); \
    bf1 = *(const short8*)((Bu) + baseB + 512); \
    bf2 = *(const short8*)((Bu) + baseB + 1024); \
    bf3 = *(const short8*)((Bu) + baseB + 1536); \
    short8 a0 = *(const short8*)((Au) + baseA + 0); \
    short8 a1 = *(const short8*)((Au) + baseA + 512); \
    short8 a2 = *(const short8*)((Au) + baseA + 1024); \
    short8 a3 = *(const short8*)((Au) + baseA + 1536); \
    ISSUE; \
    WAITPRE; \
    BAR(); \
    LGKM0(); \
    MFMA16(0, a0, a1, a2, a3); \
  } while (0)

#define PHASE_HI(Au, ISSUE, WAITPRE) do { \
    short8 a0 = *(const short8*)((Au) + baseA + 2048); \
    short8 a1 = *(const short8*)((Au) + baseA + 2560); \
    short8 a2 = *(const short8*)((Au) + baseA + 3072); \
    short8 a3 = *(const short8*)((Au) + baseA + 3584); \
    ISSUE; \
    WAITPRE; \
    BAR(); \
    LGKM0(); \
    MFMA16(1, a0, a1, a2, a3); \
  } while (0)

  // Prologue: B0A0(0), B1A1(0), B0A0(1); force tile0-kh0; rendezvous.
  STAGE_B(0, 0, 0);
  STAGE_A(0, 0, 0);
  STAGE_B(1, 0, 1);
  STAGE_A(1, 0, 1);
  STAGE_B(2, 1, 0);
  STAGE_A(2, 1, 0);
  VMW(8);
  BAR();

  for (int t = 0; t < NTT - 2; ++t) {   // t = 0..13
    const int db = t & 1;
    const int u0 = db * 2;              // this tile kh0 unit
    const int u1 = db * 2 + 1;          // this tile kh1 unit
    const int v1 = (db ^ 1) * 2 + 1;    // next tile kh1 unit
    const unsigned short* Au0 = As + u0 * 8192;
    const unsigned short* Bu0 = Bs + u0 * 8192;
    const unsigned short* Au1 = As + u1 * 8192;
    const unsigned short* Bu1 = Bs + u1 * 8192;
    PHASE_LO(Au0, Bu0, STAGE_B(v1, t + 1, 1), (void)0);   // P1
    PHASE_HI(Au0,      STAGE_A(v1, t + 1, 1), VMW(8));    // P2
    PHASE_LO(Au1, Bu1, STAGE_B(u0, t + 2, 0), (void)0);   // P3
    PHASE_HI(Au1,      STAGE_A(u0, t + 2, 0), VMW(8));    // P4
  }
  { // t = 14 (db=0): last issues = kh1(15); wind down 8 -> 4
    const unsigned short* Au0 = As;
    const unsigned short* Bu0 = Bs;
    const unsigned short* Au1 = As + 8192;
    const unsigned short* Bu1 = Bs + 8192;
    PHASE_LO(Au0, Bu0, STAGE_B(3, 15, 1), (void)0);
    PHASE_HI(Au0,      STAGE_A(3, 15, 1), VMW(8));
    PHASE_LO(Au1, Bu1, (void)0,           (void)0);
    PHASE_HI(Au1,      (void)0,           VMW(4));
  }
  { // t = 15 (db=1): force kh1(15) at P2; then pure compute
    const unsigned short* Au0 = As + 2 * 8192;
    const unsigned short* Bu0 = Bs + 2 * 8192;
    const unsigned short* Au1 = As + 3 * 8192;
    const unsigned short* Bu1 = Bs + 3 * 8192;
    PHASE_LO(Au0, Bu0, (void)0, (void)0);
    PHASE_HI(Au0,      (void)0, VMW(0));
    PHASE_LO(Au1, Bu1, (void)0, (void)0);
    PHASE_HI(Au1,      (void)0, (void)0);
  }

  // Epilogue: D[row=(lane>>4)*4+r][col=lane&15] per 16x16 frag (m89-verified).
  const int cn = lane & 15;
  const int rq = (lane >> 4) * 4;
#pragma unroll
  for (int j = 0; j < 4; ++j) {
    const int n = n0 + wn + j * 16 + cn;
    const float bv = bias[n];
#pragma unroll
    for (int i = 0; i < 8; ++i) {
      const long mb = (long)(m0 + wm + i * 16 + rq) * N_DIM + n;
#pragma unroll
      for (int r = 0; r < 4; ++r)
        C[mb + (long)r * N_DIM] = acc[i][j][r] + bv;
    }
  }
}

extern "C" void kernel_launch(void* const* d_in, const int* in_sizes, int n_in,
                              void* d_out, int out_size, void* d_ws, size_t ws_size,
                              hipStream_t stream) {
  const float* x = (const float*)d_in[0];      // [8,2048,1024]
  const float* theta = (const float*)d_in[1];  // [128,8] -> flat 1024
  const float* W = (const float*)d_in[2];      // [1024,1024]
  const float* b = (const float*)d_in[3];      // [1024]
  float* out = (float*)d_out;                  // [8,2048,1024] f32

  unsigned short* Abf = (unsigned short*)d_ws;                   // 33.5 MB
  unsigned short* Wbf = Abf + (size_t)M_DIM * K_DIM;             // +2 MB

  hipLaunchKernelGGL(prep_all, dim3(PREP_A_BLOCKS + PREP_W_BLOCKS), dim3(256), 0,
                     stream, x, theta, W, Abf, Wbf);
  hipLaunchKernelGGL(gemm_bt, dim3(N_DIM / 256, M_DIM / 256), dim3(512), 0, stream,
                     Abf, Wbf, b, out);
}